// Round 21
// baseline (143.958 us; speedup 1.0000x reference)
//
#include <hip/hip_runtime.h>
#include <hip/hip_bf16.h>
#include <type_traits>
#include <utility>

// Fused 2-layer Elman RNN + FC, round 21 (= round 18 kernel, fourth attempt;
// R18/R19/R20 benches died with container-infra errors before running).
// 8-wave blocks for 2x occupancy.
// B=16384, T=28, IN=28, H1=128, H2=64, NC=10.
// 1024 blocks x 512 thr (8 waves). Occupancy was the untested axis: R11's
// 4-wave blocks cap at 4 waves/SIMD with ~42% all-wave idle. Here:
//   P1: ALL 8 waves compute layer-1, N-split-8 (16 H1-cols each).
//   P2: waves 4-7 compute layer-2 (N-split-4, 16 H2-cols each);
//       waves 0-1 concurrently MFMA FC(t-1) from h2s[pb] (race-free:
//       other buffer, synced at B2(t-1)); waves 2-3 idle to the barrier.
// 2 barriers/step unchanged. __launch_bounds__(512,8) -> VGPR cap 64,
// 4 blocks/CU x 8 waves = 32 waves/CU = 8/SIMD (2x R11).
// Numerics identical to R11 (prepass bf16 weights, rcp-tanh, XOR-16 swizzle).

#define NBLK 1024
#define NTHR 512

typedef float  f32x4 __attribute__((ext_vector_type(4)));
typedef short  s16x8 __attribute__((ext_vector_type(8)));
typedef __bf16 b16x8 __attribute__((ext_vector_type(8)));

template <typename V, typename = void> struct mfma_ok : std::false_type {};
template <typename V>
struct mfma_ok<V, std::void_t<decltype(__builtin_amdgcn_mfma_f32_16x16x32_bf16(
    std::declval<V>(), std::declval<V>(), std::declval<f32x4>(), 0, 0, 0))>>
    : std::true_type {};
using frag_t = std::conditional_t<mfma_ok<b16x8>::value, b16x8, s16x8>;

__device__ __forceinline__ f32x4 MFMA(frag_t a, frag_t b, f32x4 c) {
  return __builtin_amdgcn_mfma_f32_16x16x32_bf16(a, b, c, 0, 0, 0);
}

__device__ __forceinline__ unsigned short f2bf_n(float f) {  // native cvt (RNE)
  __bf16 h = (__bf16)f;
  return __builtin_bit_cast(unsigned short, h);
}
__device__ __forceinline__ frag_t packx(float4 a, float4 b) {
  s16x8 r;
  r[0]=(short)f2bf_n(a.x); r[1]=(short)f2bf_n(a.y); r[2]=(short)f2bf_n(a.z); r[3]=(short)f2bf_n(a.w);
  r[4]=(short)f2bf_n(b.x); r[5]=(short)f2bf_n(b.y); r[6]=(short)f2bf_n(b.z); r[7]=(short)f2bf_n(b.w);
  return __builtin_bit_cast(frag_t, r);
}
// tanh(v) = 1 - 2/(exp(2v)+1) with fast v_rcp_f32 (exact R11 form).
__device__ __forceinline__ float tanh_fast(float v) {
  float e = __expf(2.0f * v);
  return fmaf(-2.0f, __builtin_amdgcn_rcpf(e + 1.0f), 1.0f);
}

// ---- bf16 weight cache layout in d_ws (u16 elements) ----
#define OFF_WIH1 0        // [128][32]  (K padded 28->32 with zeros)
#define OFF_WHH1 4096     // [128][128]
#define OFF_WIH2 20480    // [64][128]
#define OFF_WHH2 28672    // [64][64]
#define OFF_WFC  32768    // [10][1792]
#define WS_U16   50688

__global__ void cvt_weights(const float* __restrict__ wih1, const float* __restrict__ whh1,
                            const float* __restrict__ wih2, const float* __restrict__ whh2,
                            const float* __restrict__ wfc,  unsigned short* __restrict__ ws)
{
  int i = blockIdx.x * 256 + threadIdx.x;
  if (i < 4096) {                       // W_ih1 padded
    int r = i >> 5, c = i & 31;
    ws[OFF_WIH1 + i] = (c < 28) ? f2bf_n(wih1[r * 28 + c]) : (unsigned short)0;
    return;
  }
  i -= 4096;
  if (i < 16384) { ws[OFF_WHH1 + i] = f2bf_n(whh1[i]); return; }
  i -= 16384;
  if (i < 8192)  { ws[OFF_WIH2 + i] = f2bf_n(wih2[i]); return; }
  i -= 8192;
  if (i < 4096)  { ws[OFF_WHH2 + i] = f2bf_n(whh2[i]); return; }
  i -= 4096;
  if (i < 17920) { ws[OFF_WFC + i] = f2bf_n(wfc[i]); return; }
}

__global__ __launch_bounds__(NTHR, 8)
void rnn_mfma21(const float* __restrict__ x,
                const unsigned short* __restrict__ ws,
                const float* __restrict__ b_ih1, const float* __restrict__ b_hh1,
                const float* __restrict__ b_ih2, const float* __restrict__ b_hh2,
                const float* __restrict__ b_fc,
                float* __restrict__ out)
{
  // LDS: 8704 + 4608 + 2048 = 15,360 B; 4 blocks/CU = 61.4 KB
  __shared__ alignas(16) unsigned short h1s[2][16][136];
  __shared__ alignas(16) unsigned short h2s[2][16][72];
  __shared__ alignas(16) float red[2][16][16];

  const int tid  = threadIdx.x;
  const int w    = tid >> 6;          // wave 0..7
  const int lane = tid & 63;
  const int li   = lane & 15;         // A-row (batch) / D-col
  const int g    = lane >> 4;         // 0..3 k-group / D-row-group
  const int blk  = blockIdx.x;
  const bool isL2 = (w >= 4);
  const int  w4   = w & 3;
  // XOR-16 column swizzle: (row,col) stored at col ^ (((row>>3)&1)<<4)
  const int swr  = ((li >> 3) & 1) << 4;          // reads:  row = li
  const int swv  = ((g  >> 1) & 1) << 4;          // writes: row = g*4+r

  // ---- L1 weights (all waves): N-slice = 16 cols at w*16 ----
  const int n1 = w * 16 + li;
  frag_t wB1[4], wBi1;
  #pragma unroll
  for (int kt = 0; kt < 4; ++kt)
    wB1[kt] = *(const frag_t*)(ws + OFF_WHH1 + n1 * 128 + kt * 32 + g * 8);
  wBi1 = *(const frag_t*)(ws + OFF_WIH1 + n1 * 32 + g * 8);
  const float b1 = b_ih1[n1] + b_hh1[n1];

  // ---- L2 weights (waves 4-7): N-slice = 16 cols at w4*16 ----
  frag_t wBi2[4], wB2[2];
  float b2 = 0.0f;
  if (isL2) {
    const int n2 = w4 * 16 + li;
    #pragma unroll
    for (int kt = 0; kt < 4; ++kt)
      wBi2[kt] = *(const frag_t*)(ws + OFF_WIH2 + n2 * 128 + kt * 32 + g * 8);
    #pragma unroll
    for (int kt = 0; kt < 2; ++kt)
      wB2[kt] = *(const frag_t*)(ws + OFF_WHH2 + n2 * 64 + kt * 32 + g * 8);
    b2 = b_ih2[n2] + b_hh2[n2];
  }

  const float* xrow = x + (size_t)(blk * 16 + li) * 784 + g * 8;
  const int    cls  = (li < 10) ? li : 0;
  const unsigned short* wfp = ws + OFF_WFC + cls * 1792 + (w & 1) * 32 + g * 8;

  // loop-invariant LDS offsets
  const int rk[4] = { (g * 8) ^ swr, (32 + g * 8) ^ swr,
                      (64 + g * 8) ^ swr, (96 + g * 8) ^ swr };
  const int rfc = ((w & 1) * 32 + g * 8) ^ swr;   // FC read (waves 0,1)
  const int wc1 = ((w  * 16) ^ swv) + li;         // L1 store col
  const int wc2 = ((w4 * 16) ^ swv) + li;         // L2 store col

  f32x4 fca = {0.f, 0.f, 0.f, 0.f};

#define RNN_STEP(CB, PB, T)                                                   \
  {                                                                           \
    const int t_ = (T);                                                       \
    /* ---- P1: layer 1, all 8 waves (N-split-8) ---- */                      \
    float4 xa = *(const float4*)(xrow + t_ * 28);                             \
    float4 xb = float4{0.f, 0.f, 0.f, 0.f};                                   \
    if (g < 3) xb = *(const float4*)(xrow + t_ * 28 + 4);                     \
    f32x4 acc1 = f32x4{b1, b1, b1, b1};                                       \
    if (t_ > 0) {                                                             \
      _Pragma("unroll")                                                       \
      for (int kt = 0; kt < 4; ++kt) {                                        \
        frag_t a = *(const frag_t*)&h1s[PB][li][rk[kt]];                      \
        acc1 = MFMA(a, wB1[kt], acc1);                                        \
      }                                                                       \
    }                                                                         \
    {                                                                         \
      frag_t xA = packx(xa, xb);                                              \
      acc1 = MFMA(xA, wBi1, acc1);                                            \
    }                                                                         \
    _Pragma("unroll")                                                         \
    for (int r = 0; r < 4; ++r)                                               \
      h1s[CB][g * 4 + r][wc1] = f2bf_n(tanh_fast(acc1[r]));                   \
    __syncthreads();   /* B1: h1(t) visible */                                \
    /* ---- P2: waves 4-7 layer 2; waves 0-1 FC(t-1) ---- */                  \
    if (isL2) {                                                               \
      f32x4 acc2 = f32x4{b2, b2, b2, b2};                                     \
      _Pragma("unroll")                                                       \
      for (int kt = 0; kt < 4; ++kt) {                                        \
        frag_t a = *(const frag_t*)&h1s[CB][li][rk[kt]];                      \
        acc2 = MFMA(a, wBi2[kt], acc2);                                       \
      }                                                                       \
      if (t_ > 0) {                                                           \
        _Pragma("unroll")                                                     \
        for (int kt = 0; kt < 2; ++kt) {                                      \
          frag_t a = *(const frag_t*)&h2s[PB][li][rk[kt]];                    \
          acc2 = MFMA(a, wB2[kt], acc2);                                      \
        }                                                                     \
      }                                                                       \
      _Pragma("unroll")                                                       \
      for (int r = 0; r < 4; ++r)                                             \
        h2s[CB][g * 4 + r][wc2] = f2bf_n(tanh_fast(acc2[r]));                 \
    } else if (w < 2 && t_ > 0) {                                             \
      frag_t a   = *(const frag_t*)&h2s[PB][li][rfc];                         \
      frag_t bfc = *(const frag_t*)(wfp + (t_ - 1) * 64);                     \
      fca = MFMA(a, bfc, fca);                                                \
    }                                                                         \
    __syncthreads();   /* B2: h2(t) visible */                                \
  }

  #pragma unroll 1
  for (int t2 = 0; t2 < 28; t2 += 2) {
    RNN_STEP(0, 1, t2)
    RNN_STEP(1, 0, t2 + 1)
  }
#undef RNN_STEP

  // ---- epilogue: FC(27) (h2(27) in buffer 1), 2-way K-reduce, store ----
  if (w < 2) {
    frag_t a   = *(const frag_t*)&h2s[1][li][rfc];
    frag_t bfc = *(const frag_t*)(wfp + 27 * 64);
    fca = MFMA(a, bfc, fca);
    #pragma unroll
    for (int r = 0; r < 4; ++r)
      red[w][g * 4 + r][li] = fca[r];
  }
  __syncthreads();
  if (tid < 160) {
    const int b = tid / 10, c = tid - b * 10;
    out[(size_t)(blk * 16 + b) * 10 + c] = red[0][b][c] + red[1][b][c] + b_fc[c];
  }
}

extern "C" void kernel_launch(void* const* d_in, const int* in_sizes, int n_in,
                              void* d_out, int out_size, void* d_ws, size_t ws_size,
                              hipStream_t stream) {
  const float* x     = (const float*)d_in[0];
  const float* W_ih1 = (const float*)d_in[1];
  const float* W_hh1 = (const float*)d_in[2];
  const float* b_ih1 = (const float*)d_in[3];
  const float* b_hh1 = (const float*)d_in[4];
  const float* W_ih2 = (const float*)d_in[5];
  const float* W_hh2 = (const float*)d_in[6];
  const float* b_ih2 = (const float*)d_in[7];
  const float* b_hh2 = (const float*)d_in[8];
  const float* W_fc  = (const float*)d_in[9];
  const float* b_fc  = (const float*)d_in[10];
  unsigned short* ws = (unsigned short*)d_ws;

  cvt_weights<<<(WS_U16 + 255) / 256, 256, 0, stream>>>(W_ih1, W_hh1, W_ih2, W_hh2, W_fc, ws);
  rnn_mfma21<<<NBLK, NTHR, 0, stream>>>(x, ws, b_ih1, b_hh1, b_ih2, b_hh2, b_fc,
                                        (float*)d_out);
}

// Round 22
// 111.585 us; speedup vs baseline: 1.2901x; 1.2901x over previous
//
#include <hip/hip_runtime.h>
#include <hip/hip_bf16.h>
#include <type_traits>
#include <utility>

// Fused 2-layer Elman RNN + FC, round 22: software-pipelined phases.
// B=16384, T=28, IN=28, H1=128, H2=64, NC=10.
// 1024 blocks x 256 thr; block owns 16 batch rows; waves N-split-4.
// NEW vs R11 (62.5us): phase p computes {L1(p), L2(p-1), FC(p-2)} -- all
// data-ready after the single barrier ending phase p-1 (L1(p+1) needs only
// h1(p); h1(p-1)'s buffer is dead by then). 30 barriers total (was 56),
// and each phase has 3-4 independent MFMA chains + 12 tanh for ILP.
// Shared frag reads: h1(p-1) A-frags feed L1-rec AND L2-input; h2(p-2)
// frags feed L2-rec AND FC. 11 -> 6 ds_read_b128 per wave-phase.
// All reuse is phase-local (R12/R15 lesson: no cross-barrier registers
// beyond fca, which always persisted).
// Buffers: h1(p)->h1s[p&1] (reads 1-PAR); h2(p-1)->h2s[1-PAR] (reads PAR).
// Prepass bf16 weights in d_ws; rcp-tanh; XOR-16 swizzle (all R11).

#define NBLK 1024
#define NTHR 256

typedef float  f32x4 __attribute__((ext_vector_type(4)));
typedef short  s16x8 __attribute__((ext_vector_type(8)));
typedef __bf16 b16x8 __attribute__((ext_vector_type(8)));

template <typename V, typename = void> struct mfma_ok : std::false_type {};
template <typename V>
struct mfma_ok<V, std::void_t<decltype(__builtin_amdgcn_mfma_f32_16x16x32_bf16(
    std::declval<V>(), std::declval<V>(), std::declval<f32x4>(), 0, 0, 0))>>
    : std::true_type {};
using frag_t = std::conditional_t<mfma_ok<b16x8>::value, b16x8, s16x8>;

__device__ __forceinline__ f32x4 MFMA(frag_t a, frag_t b, f32x4 c) {
  return __builtin_amdgcn_mfma_f32_16x16x32_bf16(a, b, c, 0, 0, 0);
}

__device__ __forceinline__ unsigned short f2bf_n(float f) {  // native cvt (RNE)
  __bf16 h = (__bf16)f;
  return __builtin_bit_cast(unsigned short, h);
}
__device__ __forceinline__ frag_t packx(float4 a, float4 b) {
  s16x8 r;
  r[0]=(short)f2bf_n(a.x); r[1]=(short)f2bf_n(a.y); r[2]=(short)f2bf_n(a.z); r[3]=(short)f2bf_n(a.w);
  r[4]=(short)f2bf_n(b.x); r[5]=(short)f2bf_n(b.y); r[6]=(short)f2bf_n(b.z); r[7]=(short)f2bf_n(b.w);
  return __builtin_bit_cast(frag_t, r);
}
// tanh(v) = 1 - 2/(exp(2v)+1) with fast v_rcp_f32 (exact R11 form).
__device__ __forceinline__ float tanh_fast(float v) {
  float e = __expf(2.0f * v);
  return fmaf(-2.0f, __builtin_amdgcn_rcpf(e + 1.0f), 1.0f);
}

// ---- bf16 weight cache layout in d_ws (u16 elements) ----
#define OFF_WIH1 0        // [128][32]  (K padded 28->32 with zeros)
#define OFF_WHH1 4096     // [128][128]
#define OFF_WIH2 20480    // [64][128]
#define OFF_WHH2 28672    // [64][64]
#define OFF_WFC  32768    // [10][1792]
#define WS_U16   50688

__global__ void cvt_weights(const float* __restrict__ wih1, const float* __restrict__ whh1,
                            const float* __restrict__ wih2, const float* __restrict__ whh2,
                            const float* __restrict__ wfc,  unsigned short* __restrict__ ws)
{
  int i = blockIdx.x * 256 + threadIdx.x;
  if (i < 4096) {                       // W_ih1 padded
    int r = i >> 5, c = i & 31;
    ws[OFF_WIH1 + i] = (c < 28) ? f2bf_n(wih1[r * 28 + c]) : (unsigned short)0;
    return;
  }
  i -= 4096;
  if (i < 16384) { ws[OFF_WHH1 + i] = f2bf_n(whh1[i]); return; }
  i -= 16384;
  if (i < 8192)  { ws[OFF_WIH2 + i] = f2bf_n(wih2[i]); return; }
  i -= 8192;
  if (i < 4096)  { ws[OFF_WHH2 + i] = f2bf_n(whh2[i]); return; }
  i -= 4096;
  if (i < 17920) { ws[OFF_WFC + i] = f2bf_n(wfc[i]); return; }
}

__global__ __launch_bounds__(NTHR, 2)
void rnn_mfma22(const float* __restrict__ x,
                const unsigned short* __restrict__ ws,
                const float* __restrict__ b_ih1, const float* __restrict__ b_hh1,
                const float* __restrict__ b_ih2, const float* __restrict__ b_hh2,
                const float* __restrict__ b_fc,
                float* __restrict__ out)
{
  // LDS: 8704 + 4608 + 2048 = 15,360 B
  __shared__ alignas(16) unsigned short h1s[2][16][136];
  __shared__ alignas(16) unsigned short h2s[2][16][72];
  __shared__ alignas(16) float red[2][16][16];

  const int tid  = threadIdx.x;
  const int wn   = tid >> 6;          // wave = N-split index 0..3
  const int lane = tid & 63;
  const int li   = lane & 15;         // A-row (batch) / D-col
  const int g    = lane >> 4;         // 0..3 k-group / D-row-group
  const int blk  = blockIdx.x;
  // XOR-16 column swizzle: (row,col) stored at col ^ (((row>>3)&1)<<4)
  const int swr  = ((li >> 3) & 1) << 4;          // reads:  row = li
  const int swv  = ((g  >> 1) & 1) << 4;          // writes: row = g*4+r

  // ---- weight B-frags (as R11; compiler streams or keeps) ----
  const int n1 = wn * 32 + li;        // (+nt*16)
  const int n2 = wn * 16 + li;
  frag_t wB1[4][2], wBi1[2], wBi2[4], wB2[2];
  #pragma unroll
  for (int kt = 0; kt < 4; ++kt)
    #pragma unroll
    for (int nt = 0; nt < 2; ++nt)
      wB1[kt][nt] = *(const frag_t*)(ws + OFF_WHH1 + (n1 + nt * 16) * 128 + kt * 32 + g * 8);
  #pragma unroll
  for (int nt = 0; nt < 2; ++nt)
    wBi1[nt] = *(const frag_t*)(ws + OFF_WIH1 + (n1 + nt * 16) * 32 + g * 8);
  #pragma unroll
  for (int kt = 0; kt < 4; ++kt)
    wBi2[kt] = *(const frag_t*)(ws + OFF_WIH2 + n2 * 128 + kt * 32 + g * 8);
  #pragma unroll
  for (int kt = 0; kt < 2; ++kt)
    wB2[kt] = *(const frag_t*)(ws + OFF_WHH2 + n2 * 64 + kt * 32 + g * 8);

  float b1v[2];
  b1v[0] = b_ih1[n1] + b_hh1[n1];
  b1v[1] = b_ih1[n1 + 16] + b_hh1[n1 + 16];
  const float b2v = b_ih2[n2] + b_hh2[n2];

  const float* xrow = x + (size_t)(blk * 16 + li) * 784 + g * 8;
  const int    cls  = (li < 10) ? li : 0;
  const unsigned short* wfp = ws + OFF_WFC + cls * 1792 + (wn & 1) * 32 + g * 8;

  // loop-invariant LDS offsets
  const int rk[4] = { (g * 8) ^ swr, (32 + g * 8) ^ swr,
                      (64 + g * 8) ^ swr, (96 + g * 8) ^ swr };
  const int wcA0 = ((wn * 32) ^ swv) + li;        // L1 store cols
  const int wcA1 = ((wn * 32 + 16) ^ swv) + li;
  const int wcB  = ((wn * 16) ^ swv) + li;        // L2 store col

  f32x4 fca = {0.f, 0.f, 0.f, 0.f};

  // ================= phase 0: L1(0) only (no recurrences) =================
  {
    float4 xa = *(const float4*)(xrow);
    float4 xb = float4{0.f, 0.f, 0.f, 0.f};
    if (g < 3) xb = *(const float4*)(xrow + 4);
    frag_t xA = packx(xa, xb);
    f32x4 acc1[2];
    acc1[0] = f32x4{b1v[0], b1v[0], b1v[0], b1v[0]};
    acc1[1] = f32x4{b1v[1], b1v[1], b1v[1], b1v[1]};
    acc1[0] = MFMA(xA, wBi1[0], acc1[0]);
    acc1[1] = MFMA(xA, wBi1[1], acc1[1]);
    #pragma unroll
    for (int r = 0; r < 4; ++r) h1s[0][g * 4 + r][wcA0] = f2bf_n(tanh_fast(acc1[0][r]));
    #pragma unroll
    for (int r = 0; r < 4; ++r) h1s[0][g * 4 + r][wcA1] = f2bf_n(tanh_fast(acc1[1][r]));
    __syncthreads();
  }

  // ================= phase 1: L1(1) + L2(0) (no h2-rec, no FC) ============
  {
    frag_t h1A[4];
    #pragma unroll
    for (int kt = 0; kt < 4; ++kt) h1A[kt] = *(const frag_t*)&h1s[0][li][rk[kt]];

    float4 xa = *(const float4*)(xrow + 28);
    float4 xb = float4{0.f, 0.f, 0.f, 0.f};
    if (g < 3) xb = *(const float4*)(xrow + 28 + 4);

    f32x4 acc1[2];
    acc1[0] = f32x4{b1v[0], b1v[0], b1v[0], b1v[0]};
    acc1[1] = f32x4{b1v[1], b1v[1], b1v[1], b1v[1]};
    #pragma unroll
    for (int kt = 0; kt < 4; ++kt) {
      acc1[0] = MFMA(h1A[kt], wB1[kt][0], acc1[0]);
      acc1[1] = MFMA(h1A[kt], wB1[kt][1], acc1[1]);
    }
    {
      frag_t xA = packx(xa, xb);
      acc1[0] = MFMA(xA, wBi1[0], acc1[0]);
      acc1[1] = MFMA(xA, wBi1[1], acc1[1]);
    }

    f32x4 acc2 = f32x4{b2v, b2v, b2v, b2v};
    #pragma unroll
    for (int kt = 0; kt < 4; ++kt) acc2 = MFMA(h1A[kt], wBi2[kt], acc2);

    #pragma unroll
    for (int r = 0; r < 4; ++r) h1s[1][g * 4 + r][wcA0] = f2bf_n(tanh_fast(acc1[0][r]));
    #pragma unroll
    for (int r = 0; r < 4; ++r) h1s[1][g * 4 + r][wcA1] = f2bf_n(tanh_fast(acc1[1][r]));
    #pragma unroll
    for (int r = 0; r < 4; ++r) h2s[0][g * 4 + r][wcB] = f2bf_n(tanh_fast(acc2[r]));
    __syncthreads();
  }

  // ===== steady phases p=2..27: L1(p) + L2(p-1) + FC(p-2), 1 barrier ======
#define PHASE(PAR, P)                                                         \
  {                                                                           \
    const int p_ = (P);                                                       \
    /* shared A-frag reads: h1(p-1) from [1-PAR], h2(p-2) from [PAR] */       \
    frag_t h1A[4], h2A[2];                                                    \
    _Pragma("unroll")                                                         \
    for (int kt = 0; kt < 4; ++kt)                                            \
      h1A[kt] = *(const frag_t*)&h1s[1 - (PAR)][li][rk[kt]];                  \
    _Pragma("unroll")                                                         \
    for (int kt = 0; kt < 2; ++kt)                                            \
      h2A[kt] = *(const frag_t*)&h2s[(PAR)][li][rk[kt]];                      \
    /* L1(p) */                                                               \
    float4 xa = *(const float4*)(xrow + p_ * 28);                             \
    float4 xb = float4{0.f, 0.f, 0.f, 0.f};                                   \
    if (g < 3) xb = *(const float4*)(xrow + p_ * 28 + 4);                     \
    f32x4 acc1[2];                                                            \
    acc1[0] = f32x4{b1v[0], b1v[0], b1v[0], b1v[0]};                          \
    acc1[1] = f32x4{b1v[1], b1v[1], b1v[1], b1v[1]};                          \
    _Pragma("unroll")                                                         \
    for (int kt = 0; kt < 4; ++kt) {                                          \
      acc1[0] = MFMA(h1A[kt], wB1[kt][0], acc1[0]);                           \
      acc1[1] = MFMA(h1A[kt], wB1[kt][1], acc1[1]);                           \
    }                                                                         \
    {                                                                         \
      frag_t xA = packx(xa, xb);                                              \
      acc1[0] = MFMA(xA, wBi1[0], acc1[0]);                                   \
      acc1[1] = MFMA(xA, wBi1[1], acc1[1]);                                   \
    }                                                                         \
    /* L2(p-1): Wih2 on h1A, Whh2 on h2A */                                   \
    f32x4 acc2 = f32x4{b2v, b2v, b2v, b2v};                                   \
    _Pragma("unroll")                                                         \
    for (int kt = 0; kt < 4; ++kt) acc2 = MFMA(h1A[kt], wBi2[kt], acc2);      \
    _Pragma("unroll")                                                         \
    for (int kt = 0; kt < 2; ++kt) acc2 = MFMA(h2A[kt], wB2[kt], acc2);       \
    /* FC(p-2): reuses h2A[wn] (waves 0,1 split K=64) */                      \
    if (wn < 2) {                                                             \
      frag_t bfc = *(const frag_t*)(wfp + (p_ - 2) * 64);                     \
      fca = MFMA(h2A[wn], bfc, fca);                                          \
    }                                                                         \
    /* writes: h1(p) -> [PAR], h2(p-1) -> [1-PAR] */                          \
    _Pragma("unroll")                                                         \
    for (int r = 0; r < 4; ++r)                                               \
      h1s[PAR][g * 4 + r][wcA0] = f2bf_n(tanh_fast(acc1[0][r]));              \
    _Pragma("unroll")                                                         \
    for (int r = 0; r < 4; ++r)                                               \
      h1s[PAR][g * 4 + r][wcA1] = f2bf_n(tanh_fast(acc1[1][r]));              \
    _Pragma("unroll")                                                         \
    for (int r = 0; r < 4; ++r)                                               \
      h2s[1 - (PAR)][g * 4 + r][wcB] = f2bf_n(tanh_fast(acc2[r]));            \
    __syncthreads();                                                          \
  }

  #pragma unroll 1
  for (int p2 = 2; p2 < 28; p2 += 2) {
    PHASE(0, p2)
    PHASE(1, p2 + 1)
  }
#undef PHASE

  // ============ phase 28: L2(27) + FC(26) (h1(27) in [1], h2(26) in [0]) ==
  {
    frag_t h1A[4], h2A[2];
    #pragma unroll
    for (int kt = 0; kt < 4; ++kt) h1A[kt] = *(const frag_t*)&h1s[1][li][rk[kt]];
    #pragma unroll
    for (int kt = 0; kt < 2; ++kt) h2A[kt] = *(const frag_t*)&h2s[0][li][rk[kt]];

    f32x4 acc2 = f32x4{b2v, b2v, b2v, b2v};
    #pragma unroll
    for (int kt = 0; kt < 4; ++kt) acc2 = MFMA(h1A[kt], wBi2[kt], acc2);
    #pragma unroll
    for (int kt = 0; kt < 2; ++kt) acc2 = MFMA(h2A[kt], wB2[kt], acc2);

    if (wn < 2) {
      frag_t bfc = *(const frag_t*)(wfp + 26 * 64);
      fca = MFMA(h2A[wn], bfc, fca);
    }
    #pragma unroll
    for (int r = 0; r < 4; ++r) h2s[1][g * 4 + r][wcB] = f2bf_n(tanh_fast(acc2[r]));
    __syncthreads();
  }

  // ============ phase 29: FC(27) (h2(27) in [1]) + reduce + store =========
  if (wn < 2) {
    frag_t a   = *(const frag_t*)&h2s[1][li][rk[wn]];
    frag_t bfc = *(const frag_t*)(wfp + 27 * 64);
    fca = MFMA(a, bfc, fca);
    #pragma unroll
    for (int r = 0; r < 4; ++r)
      red[wn][g * 4 + r][li] = fca[r];
  }
  __syncthreads();
  if (tid < 160) {
    const int b = tid / 10, c = tid - b * 10;
    out[(size_t)(blk * 16 + b) * 10 + c] = red[0][b][c] + red[1][b][c] + b_fc[c];
  }
}

extern "C" void kernel_launch(void* const* d_in, const int* in_sizes, int n_in,
                              void* d_out, int out_size, void* d_ws, size_t ws_size,
                              hipStream_t stream) {
  const float* x     = (const float*)d_in[0];
  const float* W_ih1 = (const float*)d_in[1];
  const float* W_hh1 = (const float*)d_in[2];
  const float* b_ih1 = (const float*)d_in[3];
  const float* b_hh1 = (const float*)d_in[4];
  const float* W_ih2 = (const float*)d_in[5];
  const float* W_hh2 = (const float*)d_in[6];
  const float* b_ih2 = (const float*)d_in[7];
  const float* b_hh2 = (const float*)d_in[8];
  const float* W_fc  = (const float*)d_in[9];
  const float* b_fc  = (const float*)d_in[10];
  unsigned short* ws = (unsigned short*)d_ws;

  cvt_weights<<<(WS_U16 + 255) / 256, 256, 0, stream>>>(W_ih1, W_hh1, W_ih2, W_hh2, W_fc, ws);
  rnn_mfma22<<<NBLK, NTHR, 0, stream>>>(x, ws, b_ih1, b_hh1, b_ih2, b_hh2, b_fc,
                                        (float*)d_out);
}

// Round 23
// 62.568 us; speedup vs baseline: 2.3008x; 1.7834x over previous
//
#include <hip/hip_runtime.h>
#include <hip/hip_bf16.h>
#include <type_traits>
#include <utility>

// Fused 2-layer Elman RNN + FC — FINAL (= round-11 kernel, measured 62.5us,
// the session's best; rounds 12-22 tested register-carry, prefetch, VALU
// micro-cuts, 8-wave occupancy, and fused-phase pipelining — all regressed
// or spilled. This chassis is serial-dependence-bound: 56 barrier-separated
// phases, no pipe saturated (VALU 40%, MFMA 18%, LDS ~40%, HBM 5%)).
// B=16384, T=28, IN=28, H1=128, H2=64, NC=10.
// 1024 blocks x 256 thr; block owns 16 batch rows; waves N-split-4;
// 2 barriers/step; prepass bf16 weights in d_ws; rcp-tanh; unroll-2 with
// hoisted LDS offsets; XOR-16 swizzle.

#define NBLK 1024
#define NTHR 256

typedef float  f32x4 __attribute__((ext_vector_type(4)));
typedef short  s16x8 __attribute__((ext_vector_type(8)));
typedef __bf16 b16x8 __attribute__((ext_vector_type(8)));

template <typename V, typename = void> struct mfma_ok : std::false_type {};
template <typename V>
struct mfma_ok<V, std::void_t<decltype(__builtin_amdgcn_mfma_f32_16x16x32_bf16(
    std::declval<V>(), std::declval<V>(), std::declval<f32x4>(), 0, 0, 0))>>
    : std::true_type {};
using frag_t = std::conditional_t<mfma_ok<b16x8>::value, b16x8, s16x8>;

__device__ __forceinline__ f32x4 MFMA(frag_t a, frag_t b, f32x4 c) {
  return __builtin_amdgcn_mfma_f32_16x16x32_bf16(a, b, c, 0, 0, 0);
}

__device__ __forceinline__ unsigned short f2bf_n(float f) {  // native cvt (RNE)
  __bf16 h = (__bf16)f;
  return __builtin_bit_cast(unsigned short, h);
}
__device__ __forceinline__ frag_t packx(float4 a, float4 b) {
  s16x8 r;
  r[0]=(short)f2bf_n(a.x); r[1]=(short)f2bf_n(a.y); r[2]=(short)f2bf_n(a.z); r[3]=(short)f2bf_n(a.w);
  r[4]=(short)f2bf_n(b.x); r[5]=(short)f2bf_n(b.y); r[6]=(short)f2bf_n(b.z); r[7]=(short)f2bf_n(b.w);
  return __builtin_bit_cast(frag_t, r);
}
// tanh(v) = 1 - 2/(exp(2v)+1) with fast v_rcp_f32 (saturates correctly).
__device__ __forceinline__ float tanh_fast(float v) {
  float e = __expf(2.0f * v);
  return fmaf(-2.0f, __builtin_amdgcn_rcpf(e + 1.0f), 1.0f);
}

// ---- bf16 weight cache layout in d_ws (u16 elements) ----
#define OFF_WIH1 0        // [128][32]  (K padded 28->32 with zeros)
#define OFF_WHH1 4096     // [128][128]
#define OFF_WIH2 20480    // [64][128]
#define OFF_WHH2 28672    // [64][64]
#define OFF_WFC  32768    // [10][1792]
#define WS_U16   50688

__global__ void cvt_weights(const float* __restrict__ wih1, const float* __restrict__ whh1,
                            const float* __restrict__ wih2, const float* __restrict__ whh2,
                            const float* __restrict__ wfc,  unsigned short* __restrict__ ws)
{
  int i = blockIdx.x * 256 + threadIdx.x;
  if (i < 4096) {                       // W_ih1 padded
    int r = i >> 5, c = i & 31;
    ws[OFF_WIH1 + i] = (c < 28) ? f2bf_n(wih1[r * 28 + c]) : (unsigned short)0;
    return;
  }
  i -= 4096;
  if (i < 16384) { ws[OFF_WHH1 + i] = f2bf_n(whh1[i]); return; }
  i -= 16384;
  if (i < 8192)  { ws[OFF_WIH2 + i] = f2bf_n(wih2[i]); return; }
  i -= 8192;
  if (i < 4096)  { ws[OFF_WHH2 + i] = f2bf_n(whh2[i]); return; }
  i -= 4096;
  if (i < 17920) { ws[OFF_WFC + i] = f2bf_n(wfc[i]); return; }
}

__global__ __launch_bounds__(NTHR, 2)
void rnn_final(const float* __restrict__ x,
               const unsigned short* __restrict__ ws,
               const float* __restrict__ b_ih1, const float* __restrict__ b_hh1,
               const float* __restrict__ b_ih2, const float* __restrict__ b_hh2,
               const float* __restrict__ b_fc,
               float* __restrict__ out)
{
  // LDS: 8704 + 4608 + 2048 = 15,360 B
  __shared__ alignas(16) unsigned short h1s[2][16][136];
  __shared__ alignas(16) unsigned short h2s[2][16][72];
  __shared__ alignas(16) float red[2][16][16];

  const int tid  = threadIdx.x;
  const int wn   = tid >> 6;          // wave = N-split index 0..3
  const int lane = tid & 63;
  const int li   = lane & 15;         // A-row (batch) / D-col
  const int g    = lane >> 4;         // 0..3 k-group / D-row-group
  const int blk  = blockIdx.x;
  // XOR-16 column swizzle: (row,col) stored at col ^ (((row>>3)&1)<<4)
  const int swr  = ((li >> 3) & 1) << 4;          // reads:  row = li
  const int swv  = ((g  >> 1) & 1) << 4;          // writes: row = g*4+r

  // ---- weight B-frags ----
  const int n1 = wn * 32 + li;        // (+nt*16)
  const int n2 = wn * 16 + li;
  frag_t wB1[4][2], wBi1[2], wBi2[4], wB2[2];
  #pragma unroll
  for (int kt = 0; kt < 4; ++kt)
    #pragma unroll
    for (int nt = 0; nt < 2; ++nt)
      wB1[kt][nt] = *(const frag_t*)(ws + OFF_WHH1 + (n1 + nt * 16) * 128 + kt * 32 + g * 8);
  #pragma unroll
  for (int nt = 0; nt < 2; ++nt)
    wBi1[nt] = *(const frag_t*)(ws + OFF_WIH1 + (n1 + nt * 16) * 32 + g * 8);
  #pragma unroll
  for (int kt = 0; kt < 4; ++kt)
    wBi2[kt] = *(const frag_t*)(ws + OFF_WIH2 + n2 * 128 + kt * 32 + g * 8);
  #pragma unroll
  for (int kt = 0; kt < 2; ++kt)
    wB2[kt] = *(const frag_t*)(ws + OFF_WHH2 + n2 * 64 + kt * 32 + g * 8);

  float b1v[2];
  b1v[0] = b_ih1[n1] + b_hh1[n1];
  b1v[1] = b_ih1[n1 + 16] + b_hh1[n1 + 16];
  const float b2v = b_ih2[n2] + b_hh2[n2];

  const float* xrow = x + (size_t)(blk * 16 + li) * 784 + g * 8;
  const int    cls  = (li < 10) ? li : 0;
  const unsigned short* wfp = ws + OFF_WFC + cls * 1792 + (wn & 1) * 32 + g * 8;

  // loop-invariant LDS offsets (compile-time cb via unroll-2 below)
  const int rk[4] = { (g * 8) ^ swr, (32 + g * 8) ^ swr,
                      (64 + g * 8) ^ swr, (96 + g * 8) ^ swr };
  const int rfc  = (wn * 32 + g * 8) ^ swr;       // FC read (waves 0,1)
  const int wcA0 = ((wn * 32) ^ swv) + li;        // L1 store cols
  const int wcA1 = ((wn * 32 + 16) ^ swv) + li;
  const int wcB  = ((wn * 16) ^ swv) + li;        // L2 store col

  f32x4 fca = {0.f, 0.f, 0.f, 0.f};

#define RNN_STEP(CB, PB, T)                                                   \
  {                                                                           \
    const int t_ = (T);                                                       \
    /* ---- layer 1 ---- */                                                   \
    float4 xa = *(const float4*)(xrow + t_ * 28);                             \
    float4 xb = float4{0.f, 0.f, 0.f, 0.f};                                   \
    if (g < 3) xb = *(const float4*)(xrow + t_ * 28 + 4);                     \
    f32x4 acc1[2];                                                            \
    acc1[0] = f32x4{b1v[0], b1v[0], b1v[0], b1v[0]};                          \
    acc1[1] = f32x4{b1v[1], b1v[1], b1v[1], b1v[1]};                          \
    if (t_ > 0) {                                                             \
      _Pragma("unroll")                                                       \
      for (int kt = 0; kt < 4; ++kt) {                                        \
        frag_t a = *(const frag_t*)&h1s[PB][li][rk[kt]];                      \
        acc1[0] = MFMA(a, wB1[kt][0], acc1[0]);                               \
        acc1[1] = MFMA(a, wB1[kt][1], acc1[1]);                               \
      }                                                                       \
    }                                                                         \
    {                                                                         \
      frag_t xA = packx(xa, xb);                                              \
      acc1[0] = MFMA(xA, wBi1[0], acc1[0]);                                   \
      acc1[1] = MFMA(xA, wBi1[1], acc1[1]);                                   \
    }                                                                         \
    _Pragma("unroll")                                                         \
    for (int r = 0; r < 4; ++r)                                               \
      h1s[CB][g * 4 + r][wcA0] = f2bf_n(tanh_fast(acc1[0][r]));               \
    _Pragma("unroll")                                                         \
    for (int r = 0; r < 4; ++r)                                               \
      h1s[CB][g * 4 + r][wcA1] = f2bf_n(tanh_fast(acc1[1][r]));               \
    __syncthreads();   /* B1: h1(t) visible */                                \
    /* ---- layer 2 ---- */                                                   \
    f32x4 acc2 = f32x4{b2v, b2v, b2v, b2v};                                   \
    _Pragma("unroll")                                                         \
    for (int kt = 0; kt < 4; ++kt) {                                          \
      frag_t a = *(const frag_t*)&h1s[CB][li][rk[kt]];                        \
      acc2 = MFMA(a, wBi2[kt], acc2);                                         \
    }                                                                         \
    if (t_ > 0) {                                                             \
      _Pragma("unroll")                                                       \
      for (int kt = 0; kt < 2; ++kt) {                                        \
        frag_t a = *(const frag_t*)&h2s[PB][li][rk[kt]];                      \
        acc2 = MFMA(a, wB2[kt], acc2);                                        \
      }                                                                       \
    }                                                                         \
    _Pragma("unroll")                                                         \
    for (int r = 0; r < 4; ++r)                                               \
      h2s[CB][g * 4 + r][wcB] = f2bf_n(tanh_fast(acc2[r]));                   \
    __syncthreads();   /* B2: h2(t) visible */                                \
    /* ---- FC accumulation (waves 0,1 split K=64) ---- */                    \
    if (wn < 2) {                                                             \
      frag_t a   = *(const frag_t*)&h2s[CB][li][rfc];                         \
      frag_t bfc = *(const frag_t*)(wfp + t_ * 64);                           \
      fca = MFMA(a, bfc, fca);                                                \
    }                                                                         \
  }

  #pragma unroll 1
  for (int t2 = 0; t2 < 28; t2 += 2) {
    RNN_STEP(0, 1, t2)
    RNN_STEP(1, 0, t2 + 1)
  }
#undef RNN_STEP

  // ---- epilogue: 2-way K-reduce + bias + store ----
  if (wn < 2) {
    #pragma unroll
    for (int r = 0; r < 4; ++r)
      red[wn][g * 4 + r][li] = fca[r];
  }
  __syncthreads();
  if (tid < 160) {
    const int b = tid / 10, c = tid - b * 10;
    out[(size_t)(blk * 16 + b) * 10 + c] = red[0][b][c] + red[1][b][c] + b_fc[c];
  }
}

extern "C" void kernel_launch(void* const* d_in, const int* in_sizes, int n_in,
                              void* d_out, int out_size, void* d_ws, size_t ws_size,
                              hipStream_t stream) {
  const float* x     = (const float*)d_in[0];
  const float* W_ih1 = (const float*)d_in[1];
  const float* W_hh1 = (const float*)d_in[2];
  const float* b_ih1 = (const float*)d_in[3];
  const float* b_hh1 = (const float*)d_in[4];
  const float* W_ih2 = (const float*)d_in[5];
  const float* W_hh2 = (const float*)d_in[6];
  const float* b_ih2 = (const float*)d_in[7];
  const float* b_hh2 = (const float*)d_in[8];
  const float* W_fc  = (const float*)d_in[9];
  const float* b_fc  = (const float*)d_in[10];
  unsigned short* ws = (unsigned short*)d_ws;

  cvt_weights<<<(WS_U16 + 255) / 256, 256, 0, stream>>>(W_ih1, W_hh1, W_ih2, W_hh2, W_fc, ws);
  rnn_final<<<NBLK, NTHR, 0, stream>>>(x, ws, b_ih1, b_hh1, b_ih2, b_hh2, b_fc,
                                       (float*)d_out);
}